// Round 9
// baseline (115.863 us; speedup 1.0000x reference)
//
#include <hip/hip_runtime.h>
#include <cstdint>
#include <cstddef>

// Problem constants (fixed by reference setup_inputs: N=10000, D=256, pos in [0,512)^2)
#define FD    256     // feature dim
#define KS    30      // spatial k
#define KF    6       // feature k
#define CSH   4       // cell size 16 px
#define GW    32      // 32x32 cell grid
#define NCELLS (GW*GW)
#define BCAP  40      // bucket capacity/cell (Poisson lambda=9.8; P(>40)~1e-13; overflow->ovf, still exact)
#define OVCAP 128     // global overflow list capacity
#define KREG  8       // candidate key slots per lane (wave covers 512)
#define SCAPW 96      // survivors per wave (~40-60 typical; clamp guard beyond)
#define MAXC  100     // max cells per round in private path (R<=4 square = 81)
#define PIPE  10      // dot-phase row prefetch depth (divides KS=30)
#define SPCAP 512     // block-staged candidate capacity (union square, typical ~270)
#define SNS   36      // max union cells for the staged path (6x6)

// Compiler memory fence at wave-synchronous LDS phase edges (HW LDS is in-order per wave).
#define WFENCE() __threadfence_block()

// ---- K0: zero bin counters (must precede the binning atomics) --------------
__global__ __launch_bounds__(1024) void zero_kernel(int* __restrict__ cellCnt,
                                                    int* __restrict__ ovfCnt) {
  cellCnt[threadIdx.x] = 0;
  if (threadIdx.x == 0) *ovfCnt = 0;
}

// ---- K1: row L2-normalize (4 rows/block) + binning (first 40 blocks) -------
__global__ __launch_bounds__(256) void prep_bin_kernel(const float* __restrict__ x,
                                                       float* __restrict__ y,
                                                       const int2* __restrict__ pos,
                                                       int* __restrict__ cellCnt,
                                                       int2* __restrict__ bucket,
                                                       int* __restrict__ ovfCnt,
                                                       int2* __restrict__ ovf, int N) {
  const int j = blockIdx.x * 256 + threadIdx.x;
  if (j < N) {
    int2 p = pos[j];
    const int cell = (p.y >> CSH) * GW + (p.x >> CSH);
    const int s = atomicAdd(&cellCnt[cell], 1);
    const int2 e = make_int2(p.x | (p.y << 16), j);   // packed (x,y) + original index
    if (s < BCAP) bucket[cell * BCAP + s] = e;
    else { int o = atomicAdd(ovfCnt, 1); if (o < OVCAP) ovf[o] = e; }  // exactness spill
  }
  const int row = blockIdx.x * 4 + (threadIdx.x >> 6);
  if (row >= N) return;
  const int lane = threadIdx.x & 63;
  float4 v = ((const float4*)(x + (size_t)row * FD))[lane];
  float ss = v.x * v.x + v.y * v.y + v.z * v.z + v.w * v.w;
#pragma unroll
  for (int o = 32; o; o >>= 1) ss += __shfl_down(ss, o);
  ss = __shfl(ss, 0);
  const float d = fmaxf(sqrtf(ss), 1e-12f);   // F.normalize eps semantics
  float4 o4;
  o4.x = v.x / d; o4.y = v.y / d; o4.z = v.z / d; o4.w = v.w / d;
  ((float4*)(y + (size_t)row * FD))[lane] = o4;
}

// ---- K2: parallel cell-major qorder build (wave per cell, 256 blocks) ------
__global__ __launch_bounds__(256) void compact_kernel(const int* __restrict__ cellCnt,
                                                      const int2* __restrict__ bucket,
                                                      const int* __restrict__ ovfCnt,
                                                      const int2* __restrict__ ovf,
                                                      int* __restrict__ qorder, int N) {
  const int w = threadIdx.x >> 6, lane = threadIdx.x & 63;
  const int cell = blockIdx.x * 4 + w;          // 256 blocks x 4 waves = 1024 cells
  const int4* cc4 = (const int4*)cellCnt;
  int start = 0, total = 0;
#pragma unroll
  for (int c = 0; c < 4; ++c) {
    int4 v = cc4[c * 64 + lane];                // coalesced; L2-broadcast across waves
    int s0 = min(v.x, BCAP), s1 = min(v.y, BCAP), s2 = min(v.z, BCAP), s3 = min(v.w, BCAP);
    int s = s0 + s1 + s2 + s3;
    int incl = s;
#pragma unroll
    for (int o = 1; o < 64; o <<= 1) { int u = __shfl_up(incl, o); if (lane >= o) incl += u; }
    const int cid0 = (c * 64 + lane) * 4;       // first cell id in this lane-chunk
    if (cell >= cid0 && cell < cid0 + 4) {      // owning lane computes the start
      int p = total + (incl - s);
      if (cell - cid0 > 0) p += s0;
      if (cell - cid0 > 1) p += s1;
      if (cell - cid0 > 2) p += s2;
      start = p;
    }
    total += __shfl(incl, 63);                  // running base of previous chunks
  }
  start = __shfl(start, (cell >> 2) & 63);      // broadcast from the owning lane
  const int cnt = min(cellCnt[cell], BCAP);
  for (int s = lane; s < cnt; s += 64)
    qorder[start + s] = bucket[cell * BCAP + s].y;
  if (cell == NCELLS - 1) {                     // append overflow queries (~never)
    const int on = min(*ovfCnt, OVCAP);
    for (int o = lane; o < on; o += 64) qorder[total + o] = ovf[o].y;
  }
}

// ---- K3: wave-per-query exact spatial top-30 + cosine top-6 ----------------
// New in R9: the block's 4 same-cell queries share ONE LDS staging of the
// union (5x5/6x6) square's candidate entries (3 barriers/block), so each
// wave's key build is a direct LDS read — no per-wave binary search or
// gathered bucket loads on the hot path. Private (barrier-free) fallback
// for ring growth R>=3 / oversized unions keeps exactness.
__global__ __launch_bounds__(256, 6) void graph_kernel(const int2* __restrict__ pos,
                                                       const int* __restrict__ cellCnt,
                                                       const int2* __restrict__ bucket,
                                                       const int* __restrict__ ovfCnt,
                                                       const int2* __restrict__ ovf,
                                                       const int* __restrict__ qorder,
                                                       const float* __restrict__ fn,
                                                       float* __restrict__ outI,
                                                       float* __restrict__ outW, int N) {
  __shared__ float qf[4][FD];
  __shared__ unsigned long long surv[4][SCAPW];
  __shared__ int pfx[4][MAXC + 1];     // private-path cell prefix
  __shared__ int cbase[4][MAXC];
  __shared__ int hist[4][64];
  __shared__ float sims[4][KS];
  __shared__ int selj[4][KS];
  __shared__ int wsel[4][KF];
  __shared__ int kd2[4];
  // block-shared candidate staging
  __shared__ int2 spp[SPCAP];
  __shared__ int spfx[SNS + 1];
  __shared__ int sbase[SNS];
  __shared__ int bcx[4], bcy[4];
  __shared__ int sM;

  const int w = threadIdx.x >> 6, lane = threadIdx.x & 63;
  const int t = threadIdx.x;
  const int qi0 = blockIdx.x * 4 + w;
  const int qi = min(qi0, N - 1);         // clamp so all waves reach the barriers
  const int i = qorder[qi];               // cell-major query order (spatial locality)

  float* qfw = qf[w];
  unsigned long long* survw = surv[w];
  int* pfxw = pfx[w];
  int* basew = cbase[w];
  int* histw = hist[w];
  float* simsw = sims[w];
  int* seljw = selj[w];
  int* wselw = wsel[w];

  const int2 q = pos[i];
  const int qx = q.x, qy = q.y;
  const int cx = qx >> CSH, cy = qy >> CSH;
  const int ovfN = min(*ovfCnt, OVCAP);   // ~always 0; uniform L2 broadcast load

  ((float4*)qfw)[lane] = ((const float4*)(fn + (size_t)i * FD))[lane];  // 1 KB query row
  if (lane == 0) { bcx[w] = cx; bcy[w] = cy; }
  __syncthreads();

  // ---- block-uniform union box of the 4 queries' R=2 squares ----
  const int ux0 = max(min(min(bcx[0], bcx[1]), min(bcx[2], bcx[3])) - 2, 0);
  const int ux1 = min(max(max(bcx[0], bcx[1]), max(bcx[2], bcx[3])) + 2, GW - 1);
  const int uy0 = max(min(min(bcy[0], bcy[1]), min(bcy[2], bcy[3])) - 2, 0);
  const int uy1 = min(max(max(bcy[0], bcy[1]), max(bcy[2], bcy[3])) + 2, GW - 1);
  const int uw = ux1 - ux0 + 1, uh = uy1 - uy0 + 1;
  const int nsu = uw * uh;
  const bool sharedOK = (nsu <= SNS);     // block-uniform (from shared bcx/bcy)
  int M_s = -1;
  if (sharedOK) {
    if (t < nsu) {
      const int cid = (uy0 + t / uw) * GW + (ux0 + t % uw);
      sbase[t] = cid * BCAP;
      spfx[t] = min(cellCnt[cid], BCAP);  // counts; scanned in place below
    }
    __syncthreads();
    if (t == 0) {
      int run = 0;
      for (int c = 0; c < nsu; ++c) { int v = spfx[c]; spfx[c] = run; run += v; }
      spfx[nsu] = run;
      sM = (run <= SPCAP) ? run : -1;     // overflow -> private fallback (exact)
    }
    __syncthreads();
    M_s = sM;
    if (M_s >= 0) {
      for (int m = t; m < M_s; m += 256) {
        int c = 0;                        // binary search over <=36 cells, once/block
#pragma unroll
        for (int st = 32; st; st >>= 1) { int nc = c + st; if (nc < nsu && spfx[nc] <= m) c = nc; }
        spp[m] = bucket[sbase[c] + (m - spfx[c])];   // coalesced within a cell run
      }
    }
    __syncthreads();
  }
  if (qi0 >= N) return;                   // after all barriers (defensive; N=10000 exact)

  int R = 2;
  int sn = 0;
  bool useStaged = (sharedOK && M_s >= 0);
  for (;;) {
    int M;
    if (useStaged) {
      M = M_s;                            // staged path: keys read straight from LDS
    } else {
      // ---- private path: list own (2R+1)^2 square; chunked shuffle prefix ----
      const int W = 2 * R + 1;
      const int ns = min(W * W, MAXC);
      int run = 0;
      for (int cb = 0; cb < ns; cb += 64) {
        const int s = cb + lane;
        int cnt = 0, base = 0;
        if (s < ns) {
          int dy = s / W - R, dx = s % W - R;
          int yy = cy + dy, xx = cx + dx;
          if (yy >= 0 && yy < GW && xx >= 0 && xx < GW) {
            int cid = yy * GW + xx;
            cnt = min(cellCnt[cid], BCAP);
            base = cid * BCAP;
          }
        }
        int incl = cnt;
#pragma unroll
        for (int o = 1; o < 64; o <<= 1) { int u = __shfl_up(incl, o); if (lane >= o) incl += u; }
        if (s < ns) { pfxw[s] = run + incl - cnt; basew[s] = base; }
        run += __shfl(incl, 63);
      }
      if (lane == 0) pfxw[ns] = run;
      WFENCE();
      M = run;
    }
    const int MM = min(M + ovfN, 64 * KREG);   // clamp guard (drop semantics unchanged)

    // ---- build candidate keys into registers: (d2<<16)|j, self -> ~0 ----
    unsigned long long kreg[KREG];
#pragma unroll
    for (int s8 = 0; s8 < KREG; ++s8) {
      kreg[s8] = ~0ull;
      const int m = lane + 64 * s8;
      if (m < MM) {
        int2 e;
        if (m < M) {
          if (useStaged) {
            e = spp[m];                   // direct LDS read, 2-way aliasing (free)
          } else {
            const int W = 2 * R + 1;
            const int ns = min(W * W, MAXC);
            int c = 0;                    // binary search: largest c, pfx[c] <= m
#pragma unroll
            for (int st = 64; st; st >>= 1) { int nc = c + st; if (nc < ns && pfxw[nc] <= m) c = nc; }
            e = bucket[basew[c] + (m - pfxw[c])];
          }
        } else {
          e = ovf[m - M];
        }
        const int j = e.y;
        if (j != i) {
          int x = e.x & 0xffff, y = e.x >> 16;
          int dx = qx - x, dy = qy - y;
          unsigned d2 = (unsigned)(dx * dx + dy * dy);
          kreg[s8] = (((unsigned long long)d2) << 16) | (unsigned)j;
        }
      }
    }

    // ---- 64-bucket d2 histogram (width 64) -> threshold via ballot ----
    histw[lane] = 0;
    WFENCE();
#pragma unroll
    for (int s8 = 0; s8 < KREG; ++s8)
      if (kreg[s8] != ~0ull)
        atomicAdd(&histw[min((int)(kreg[s8] >> 22), 63)], 1);   // key>>22 == d2>>6
    WFENCE();
    int cum = histw[lane];
#pragma unroll
    for (int o = 1; o < 64; o <<= 1) { int u = __shfl_up(cum, o); if (lane >= o) cum += u; }
    const unsigned long long bal = __ballot(cum >= KS);
    unsigned long long Tk;
    if (bal == 0) Tk = 0x7fffffffull << 16;           // all valid keys survive
    else {
      int bb = __ffsll((unsigned long long)bal) - 1;  // first bucket with cum>=KS
      Tk = (bb == 63) ? (0x7fffffffull << 16) : (((unsigned long long)(bb + 1) << 6) << 16);
    }

    // ---- ballot-prefix compact of survivors (no atomics) ----
    int sbase2 = 0;
#pragma unroll
    for (int s8 = 0; s8 < KREG; ++s8) {
      const bool p = kreg[s8] < Tk;                   // self ~0 never survives
      const unsigned long long mask = __ballot(p);
      if (p) {
        int idx = sbase2 + __popcll(mask & ((1ull << lane) - 1));
        if (idx < SCAPW) survw[idx] = kreg[s8];       // clamp guard, P~1e-40
      }
      sbase2 += __popcll(mask);
    }
    sn = min(sbase2, SCAPW);
    WFENCE();

    // ---- exact stable top-KS by rank-by-count over survivors ----
    for (int p = lane; p < sn; p += 64) {
      const unsigned long long kp = survw[p];
      int r = 0;
      for (int s = 0; s < sn; ++s) r += (survw[s] < kp) ? 1 : 0;  // LDS broadcast reads
      if (r < KS) seljw[r] = (int)(kp & 0xffffu);
      if (r == KS - 1) kd2[w] = (int)(kp >> 16);
    }
    WFENCE();

    // ---- exactness: 30th d2 must strictly beat anything outside OWN square ----
    bool done = false;
    if (sn >= KS) {
      const int kthd2 = kd2[w];
      int sg = 1 << 15;                 // "infinite" when all sides reach the domain edge
      if (cx - R > 0)      sg = min(sg, qx - ((cx - R) << CSH));
      if (cx + R < GW - 1) sg = min(sg, (((cx + R) << CSH) + 15) - qx);
      if (cy - R > 0)      sg = min(sg, qy - ((cy - R) << CSH));
      if (cy + R < GW - 1) sg = min(sg, (((cy + R) << CSH) + 15) - qy);
      done = kthd2 < (sg + 1) * (sg + 1);
    }
    if (done) break;
    ++R;                                // rare: re-collect the bigger square privately
    useStaged = false;
  }

  // ---- cosine sims: wave-cooperative coalesced row reads (proven summation order),
  //      PIPE-deep software pipeline; 30 independent shfl trees interleave ----
  const float4 q4v = ((const float4*)qfw)[lane];
  float4 fbuf[PIPE];
#pragma unroll
  for (int c = 0; c < PIPE; ++c)
    fbuf[c] = ((const float4*)(fn + (size_t)seljw[c] * FD))[lane];
#pragma unroll
  for (int c = 0; c < KS; ++c) {
    const float4 f = fbuf[c % PIPE];
    if (c + PIPE < KS)
      fbuf[c % PIPE] = ((const float4*)(fn + (size_t)seljw[c + PIPE] * FD))[lane];
    float d = f.x * q4v.x + f.y * q4v.y + f.z * q4v.z + f.w * q4v.w;
#pragma unroll
    for (int o = 32; o; o >>= 1) d += __shfl_down(d, o);
    if (lane == 0) simsw[c] = d;
  }
  WFENCE();

  // ---- stable top-KF (desc value, asc index on ties) ----
  if (lane < KS) {
    const float simv = simsw[lane];
    int r = 0;
    for (int s = 0; s < KS; ++s) {
      const float so = simsw[s];
      if (so > simv || (so == simv && s < lane)) ++r;
    }
    if (r < KF) wselw[r] = lane;
  }
  WFENCE();

  // ---- softmax over the 6 selected; lanes 0-5 write (same math as R1-8) ----
  if (lane < KF) {
    const float m = simsw[wselw[0]];    // rank 0 == max
    float sum = 0.f, my = 0.f;
#pragma unroll
    for (int r = 0; r < KF; ++r) {
      float e = expf(simsw[wselw[r]] - m);
      sum += e;
      if (r == lane) my = e;
    }
    outI[(size_t)i * KF + lane] = (float)seljw[wselw[lane]];
    outW[(size_t)i * KF + lane] = my / sum;
  }
}

extern "C" void kernel_launch(void* const* d_in, const int* in_sizes, int n_in,
                              void* d_out, int out_size, void* d_ws, size_t ws_size,
                              hipStream_t stream) {
  const float* feat = (const float*)d_in[0];   // [N, 256] fp32
  const int2* pos = (const int2*)d_in[1];      // [N, 2] int32
  const int N = in_sizes[1] / 2;

  char* ws = (char*)d_ws;
  float* fn = (float*)ws;                        // N*256 f32 = 10.24 MB
  size_t off = (size_t)N * FD * sizeof(float);
  int* cellCnt = (int*)(ws + off);  off += NCELLS * sizeof(int);
  int* ovfCnt  = (int*)(ws + off);  off += 2 * sizeof(int);            // keep 8B align
  int2* bucket = (int2*)(ws + off); off += (size_t)NCELLS * BCAP * sizeof(int2);
  int2* ovf    = (int2*)(ws + off); off += OVCAP * sizeof(int2);
  int* qorder  = (int*)(ws + off);  off += (size_t)N * sizeof(int);    // ~10.7 MB total

  float* out = (float*)d_out;                    // [N*6] indices (as f32) ++ [N*6] weights

  zero_kernel<<<1, 1024, 0, stream>>>(cellCnt, ovfCnt);
  prep_bin_kernel<<<(N + 3) / 4, 256, 0, stream>>>(feat, fn, pos, cellCnt, bucket,
                                                   ovfCnt, ovf, N);
  compact_kernel<<<NCELLS / 4, 256, 0, stream>>>(cellCnt, bucket, ovfCnt, ovf, qorder, N);
  graph_kernel<<<(N + 3) / 4, 256, 0, stream>>>(pos, cellCnt, bucket, ovfCnt, ovf, qorder,
                                                fn, out, out + (size_t)N * KF, N);
}

// Round 10
// 111.516 us; speedup vs baseline: 1.0390x; 1.0390x over previous
//
#include <hip/hip_runtime.h>
#include <cstdint>
#include <cstddef>

// Problem constants (fixed by reference setup_inputs: N=10000, D=256, pos in [0,512)^2)
#define FD    256     // feature dim
#define KS    30      // spatial k
#define KF    6       // feature k
#define CSH   4       // cell size 16 px
#define GW    32      // 32x32 cell grid
#define NCELLS (GW*GW)
#define BCAP  40      // bucket capacity/cell (Poisson lambda=9.8; P(>40)~1e-13; overflow->ovf, still exact)
#define OVCAP 128     // global overflow list capacity
#define KREG  8       // candidate key slots per lane (wave covers 512; R=2 square ~245)
#define SCAPW 96      // survivors per wave (~40-60 typical; clamp guard beyond)
#define MAXC  100     // max cells per round (R<=4 square = 81)
#define PIPE  5       // dot-phase prefetch depth (divides KS; PIPE=10 spilled to scratch in R9 — keep 5)

// Compiler memory fence at wave-synchronous LDS phase edges (HW LDS is in-order per wave).
#define WFENCE() __threadfence_block()

// ---- K0: zero bin counters (must precede the binning atomics) --------------
__global__ __launch_bounds__(1024) void zero_kernel(int* __restrict__ cellCnt,
                                                    int* __restrict__ ovfCnt) {
  cellCnt[threadIdx.x] = 0;
  if (threadIdx.x == 0) *ovfCnt = 0;
}

// ---- K1: row L2-normalize (4 rows/block) + binning (first 40 blocks) -------
__global__ __launch_bounds__(256) void prep_bin_kernel(const float* __restrict__ x,
                                                       float* __restrict__ y,
                                                       const int2* __restrict__ pos,
                                                       int* __restrict__ cellCnt,
                                                       int2* __restrict__ bucket,
                                                       int* __restrict__ ovfCnt,
                                                       int2* __restrict__ ovf, int N) {
  const int j = blockIdx.x * 256 + threadIdx.x;
  if (j < N) {
    int2 p = pos[j];
    const int cell = (p.y >> CSH) * GW + (p.x >> CSH);
    const int s = atomicAdd(&cellCnt[cell], 1);
    const int2 e = make_int2(p.x | (p.y << 16), j);   // packed (x,y) + original index
    if (s < BCAP) bucket[cell * BCAP + s] = e;
    else { int o = atomicAdd(ovfCnt, 1); if (o < OVCAP) ovf[o] = e; }  // exactness spill
  }
  const int row = blockIdx.x * 4 + (threadIdx.x >> 6);
  if (row >= N) return;
  const int lane = threadIdx.x & 63;
  float4 v = ((const float4*)(x + (size_t)row * FD))[lane];
  float ss = v.x * v.x + v.y * v.y + v.z * v.z + v.w * v.w;
#pragma unroll
  for (int o = 32; o; o >>= 1) ss += __shfl_down(ss, o);
  ss = __shfl(ss, 0);
  const float d = fmaxf(sqrtf(ss), 1e-12f);   // F.normalize eps semantics
  float4 o4;
  o4.x = v.x / d; o4.y = v.y / d; o4.z = v.z / d; o4.w = v.w / d;
  ((float4*)(y + (size_t)row * FD))[lane] = o4;
}

// ---- K2: parallel cell-major qorder build (wave per cell, 256 blocks) ------
__global__ __launch_bounds__(256) void compact_kernel(const int* __restrict__ cellCnt,
                                                      const int2* __restrict__ bucket,
                                                      const int* __restrict__ ovfCnt,
                                                      const int2* __restrict__ ovf,
                                                      int* __restrict__ qorder, int N) {
  const int w = threadIdx.x >> 6, lane = threadIdx.x & 63;
  const int cell = blockIdx.x * 4 + w;          // 256 blocks x 4 waves = 1024 cells
  const int4* cc4 = (const int4*)cellCnt;
  int start = 0, total = 0;
#pragma unroll
  for (int c = 0; c < 4; ++c) {
    int4 v = cc4[c * 64 + lane];                // coalesced; L2-broadcast across waves
    int s0 = min(v.x, BCAP), s1 = min(v.y, BCAP), s2 = min(v.z, BCAP), s3 = min(v.w, BCAP);
    int s = s0 + s1 + s2 + s3;
    int incl = s;
#pragma unroll
    for (int o = 1; o < 64; o <<= 1) { int u = __shfl_up(incl, o); if (lane >= o) incl += u; }
    const int cid0 = (c * 64 + lane) * 4;       // first cell id in this lane-chunk
    if (cell >= cid0 && cell < cid0 + 4) {      // owning lane computes the start
      int p = total + (incl - s);
      if (cell - cid0 > 0) p += s0;
      if (cell - cid0 > 1) p += s1;
      if (cell - cid0 > 2) p += s2;
      start = p;
    }
    total += __shfl(incl, 63);                  // running base of previous chunks
  }
  start = __shfl(start, (cell >> 2) & 63);      // broadcast from the owning lane
  const int cnt = min(cellCnt[cell], BCAP);
  for (int s = lane; s < cnt; s += 64)
    qorder[start + s] = bucket[cell * BCAP + s].y;
  if (cell == NCELLS - 1) {                     // append overflow queries (~never)
    const int on = min(*ovfCnt, OVCAP);
    for (int o = lane; o < on; o += 64) qorder[total + o] = ovf[o].y;
  }
}

// ---- K3: wave-per-query exact spatial top-30 + cosine top-6 (no barriers) --
// Byte-for-byte the round-8 kernel (best profiled: 46.6 us) with ONE change:
// XCD-aware block swizzle so each XCD (blockIdx%8 heuristic) works a
// contiguous cell-range; per-XCD L2 working set drops from ~10.5 MB (whole
// fn+bucket) to ~1.5 MB (< 4 MiB/XCD L2). Pure locality heuristic — the
// mapping is bijective, so correctness never depends on XCD assignment.
__global__ __launch_bounds__(256, 6) void graph_kernel(const int2* __restrict__ pos,
                                                       const int* __restrict__ cellCnt,
                                                       const int2* __restrict__ bucket,
                                                       const int* __restrict__ ovfCnt,
                                                       const int2* __restrict__ ovf,
                                                       const int* __restrict__ qorder,
                                                       const float* __restrict__ fn,
                                                       float* __restrict__ outI,
                                                       float* __restrict__ outW, int N) {
  __shared__ float qf[4][FD];
  __shared__ unsigned long long surv[4][SCAPW];
  __shared__ int pfx[4][MAXC + 1];
  __shared__ int cbase[4][MAXC];
  __shared__ int hist[4][64];
  __shared__ float sims[4][KS];
  __shared__ int selj[4][KS];
  __shared__ int wsel[4][KF];
  __shared__ int kd2[4];

  const int w = threadIdx.x >> 6, lane = threadIdx.x & 63;

  // XCD swizzle: blockIdx 8j+x -> x*(nb/8)+j gives XCD x a contiguous block range.
  const int nb = gridDim.x;
  const int grp = nb >> 3;                // 312 for nb=2500
  const int lim = grp << 3;               // 2496; leftovers map to themselves
  const int b = (blockIdx.x < lim) ? ((blockIdx.x & 7) * grp + (blockIdx.x >> 3))
                                   : blockIdx.x;

  const int qi = b * 4 + w;
  if (qi >= N) return;                    // wave-uniform; no block barriers anywhere
  const int i = qorder[qi];               // cell-major query order (spatial locality)

  float* qfw = qf[w];
  unsigned long long* survw = surv[w];
  int* pfxw = pfx[w];
  int* basew = cbase[w];
  int* histw = hist[w];
  float* simsw = sims[w];
  int* seljw = selj[w];
  int* wselw = wsel[w];

  const int2 q = pos[i];
  const int qx = q.x, qy = q.y;
  const int cx = qx >> CSH, cy = qy >> CSH;
  const int ovfN = min(*ovfCnt, OVCAP);   // ~always 0; uniform L2 broadcast load

  ((float4*)qfw)[lane] = ((const float4*)(fn + (size_t)i * FD))[lane];  // 1 KB query row
  WFENCE();

  int R = 2;
  int sn = 0;
  for (;;) {
    // ---- list the (2R+1)^2 square's cells; chunked shuffle prefix-scan ----
    const int W = 2 * R + 1;
    const int ns = min(W * W, MAXC);
    int run = 0;
    for (int cb = 0; cb < ns; cb += 64) {
      const int s = cb + lane;
      int cnt = 0, base = 0;
      if (s < ns) {
        int dy = s / W - R, dx = s % W - R;
        int yy = cy + dy, xx = cx + dx;
        if (yy >= 0 && yy < GW && xx >= 0 && xx < GW) {
          int cid = yy * GW + xx;
          cnt = min(cellCnt[cid], BCAP);   // parallel global loads, L2-hot
          base = cid * BCAP;
        }
      }
      int incl = cnt;
#pragma unroll
      for (int o = 1; o < 64; o <<= 1) { int u = __shfl_up(incl, o); if (lane >= o) incl += u; }
      if (s < ns) { pfxw[s] = run + incl - cnt; basew[s] = base; }
      run += __shfl(incl, 63);
    }
    if (lane == 0) pfxw[ns] = run;
    WFENCE();
    const int M = run;
    const int MM = min(M + ovfN, 64 * KREG);   // clamp guard (same drop semantics as before)

    // ---- build candidate keys into registers: (d2<<16)|j, self -> ~0 ----
    unsigned long long kreg[KREG];
#pragma unroll
    for (int s8 = 0; s8 < KREG; ++s8) {
      kreg[s8] = ~0ull;
      const int m = lane + 64 * s8;
      if (m < MM) {
        int2 e;
        if (m < M) {
          int c = 0;                          // binary search: largest c, pfx[c] <= m
#pragma unroll
          for (int st = 64; st; st >>= 1) { int nc = c + st; if (nc < ns && pfxw[nc] <= m) c = nc; }
          e = bucket[basew[c] + (m - pfxw[c])];
        } else {
          e = ovf[m - M];
        }
        const int j = e.y;
        if (j != i) {
          int x = e.x & 0xffff, y = e.x >> 16;
          int dx = qx - x, dy = qy - y;
          unsigned d2 = (unsigned)(dx * dx + dy * dy);
          kreg[s8] = (((unsigned long long)d2) << 16) | (unsigned)j;
        }
      }
    }

    // ---- 64-bucket d2 histogram (width 64) -> threshold via ballot ----
    histw[lane] = 0;
    WFENCE();
#pragma unroll
    for (int s8 = 0; s8 < KREG; ++s8)
      if (kreg[s8] != ~0ull)
        atomicAdd(&histw[min((int)(kreg[s8] >> 22), 63)], 1);   // key>>22 == d2>>6
    WFENCE();
    int cum = histw[lane];
#pragma unroll
    for (int o = 1; o < 64; o <<= 1) { int u = __shfl_up(cum, o); if (lane >= o) cum += u; }
    const unsigned long long bal = __ballot(cum >= KS);
    unsigned long long Tk;
    if (bal == 0) Tk = 0x7fffffffull << 16;           // all valid keys survive
    else {
      int bb = __ffsll((unsigned long long)bal) - 1;  // first bucket with cum>=KS
      Tk = (bb == 63) ? (0x7fffffffull << 16) : (((unsigned long long)(bb + 1) << 6) << 16);
    }

    // ---- ballot-prefix compact of survivors (no atomics) ----
    int sbase = 0;
#pragma unroll
    for (int s8 = 0; s8 < KREG; ++s8) {
      const bool p = kreg[s8] < Tk;                   // self ~0 never survives
      const unsigned long long mask = __ballot(p);
      if (p) {
        int idx = sbase + __popcll(mask & ((1ull << lane) - 1));
        if (idx < SCAPW) survw[idx] = kreg[s8];       // clamp guard, P~1e-40
      }
      sbase += __popcll(mask);
    }
    sn = min(sbase, SCAPW);
    WFENCE();

    // ---- exact stable top-KS by rank-by-count over survivors ----
    for (int p = lane; p < sn; p += 64) {
      const unsigned long long kp = survw[p];
      int r = 0;
      for (int s = 0; s < sn; ++s) r += (survw[s] < kp) ? 1 : 0;  // LDS broadcast reads
      if (r < KS) seljw[r] = (int)(kp & 0xffffu);
      if (r == KS - 1) kd2[w] = (int)(kp >> 16);
    }
    WFENCE();

    // ---- exactness: 30th d2 must strictly beat anything outside the square ----
    bool done = false;
    if (sn >= KS) {
      const int kthd2 = kd2[w];
      int sg = 1 << 15;                 // "infinite" when all sides reach the domain edge
      if (cx - R > 0)      sg = min(sg, qx - ((cx - R) << CSH));
      if (cx + R < GW - 1) sg = min(sg, (((cx + R) << CSH) + 15) - qx);
      if (cy - R > 0)      sg = min(sg, qy - ((cy - R) << CSH));
      if (cy + R < GW - 1) sg = min(sg, (((cy + R) << CSH) + 15) - qy);
      done = kthd2 < (sg + 1) * (sg + 1);
    }
    if (done) break;
    ++R;                                // rare: re-scan the bigger square from scratch
  }

  // ---- cosine sims: wave-cooperative coalesced row reads (proven summation order),
  //      PIPE-deep software pipeline; 30 independent shfl trees interleave ----
  const float4 q4v = ((const float4*)qfw)[lane];
  float4 fbuf[PIPE];
#pragma unroll
  for (int c = 0; c < PIPE; ++c)
    fbuf[c] = ((const float4*)(fn + (size_t)seljw[c] * FD))[lane];
#pragma unroll
  for (int c = 0; c < KS; ++c) {
    const float4 f = fbuf[c % PIPE];
    if (c + PIPE < KS)
      fbuf[c % PIPE] = ((const float4*)(fn + (size_t)seljw[c + PIPE] * FD))[lane];
    float d = f.x * q4v.x + f.y * q4v.y + f.z * q4v.z + f.w * q4v.w;
#pragma unroll
    for (int o = 32; o; o >>= 1) d += __shfl_down(d, o);
    if (lane == 0) simsw[c] = d;
  }
  WFENCE();

  // ---- stable top-KF (desc value, asc index on ties) ----
  if (lane < KS) {
    const float simv = simsw[lane];
    int r = 0;
    for (int s = 0; s < KS; ++s) {
      const float so = simsw[s];
      if (so > simv || (so == simv && s < lane)) ++r;
    }
    if (r < KF) wselw[r] = lane;
  }
  WFENCE();

  // ---- softmax over the 6 selected; lanes 0-5 write (same math as R1-9) ----
  if (lane < KF) {
    const float m = simsw[wselw[0]];    // rank 0 == max
    float sum = 0.f, my = 0.f;
#pragma unroll
    for (int r = 0; r < KF; ++r) {
      float e = expf(simsw[wselw[r]] - m);
      sum += e;
      if (r == lane) my = e;
    }
    outI[(size_t)i * KF + lane] = (float)seljw[wselw[lane]];
    outW[(size_t)i * KF + lane] = my / sum;
  }
}

extern "C" void kernel_launch(void* const* d_in, const int* in_sizes, int n_in,
                              void* d_out, int out_size, void* d_ws, size_t ws_size,
                              hipStream_t stream) {
  const float* feat = (const float*)d_in[0];   // [N, 256] fp32
  const int2* pos = (const int2*)d_in[1];      // [N, 2] int32
  const int N = in_sizes[1] / 2;

  char* ws = (char*)d_ws;
  float* fn = (float*)ws;                        // N*256 f32 = 10.24 MB
  size_t off = (size_t)N * FD * sizeof(float);
  int* cellCnt = (int*)(ws + off);  off += NCELLS * sizeof(int);
  int* ovfCnt  = (int*)(ws + off);  off += 2 * sizeof(int);            // keep 8B align
  int2* bucket = (int2*)(ws + off); off += (size_t)NCELLS * BCAP * sizeof(int2);
  int2* ovf    = (int2*)(ws + off); off += OVCAP * sizeof(int2);
  int* qorder  = (int*)(ws + off);  off += (size_t)N * sizeof(int);    // ~10.7 MB total

  float* out = (float*)d_out;                    // [N*6] indices (as f32) ++ [N*6] weights

  zero_kernel<<<1, 1024, 0, stream>>>(cellCnt, ovfCnt);
  prep_bin_kernel<<<(N + 3) / 4, 256, 0, stream>>>(feat, fn, pos, cellCnt, bucket,
                                                   ovfCnt, ovf, N);
  compact_kernel<<<NCELLS / 4, 256, 0, stream>>>(cellCnt, bucket, ovfCnt, ovf, qorder, N);
  graph_kernel<<<(N + 3) / 4, 256, 0, stream>>>(pos, cellCnt, bucket, ovfCnt, ovf, qorder,
                                                fn, out, out + (size_t)N * KF, N);
}